// Round 3
// baseline (118.742 us; speedup 1.0000x reference)
//
#include <hip/hip_runtime.h>

// Legendre2 via split-precision MFMA, v3: 16-wave blocks for 4 waves/SIMD.
// W_i = Z @ (coef_i * Tnorm_i)^T  as f16 hi/lo 3-term MFMA (f32 accum),
// elementwise Legendre fold in f32 regs (immediate fold, no W array),
// epilogue P6 @ C^T + beta as bf16 hi/lo 3-term MFMA.
// N=524288, D=64, K=64, O=32, DEGREE=6.

typedef _Float16 f16x8 __attribute__((ext_vector_type(8)));
typedef short    s16x8 __attribute__((ext_vector_type(8)));
typedef float    f32x4 __attribute__((ext_vector_type(4)));

#define NN      524288
#define BLOCKS  256
#define THREADS 1024
#define NWAVES  16
#define ROWS_PER_WAVE 128
#define NITER   4                        // 4 x 32 rows per wave

// LDS byte offsets
#define BH_OFF    0                      // 48 frags * 1 KB (f16 hi of A)
#define BL_OFF    49152                  // 48 frags * 1 KB (f16 lo of A)
#define CF_OFF    98304                  // 8 frags * 1 KB (bf16 h/l of C)
#define SCALE_OFF 106496                 // 384 f32 scales
#define SCR_OFF   108032                 // 16 waves * 2 KB transpose scratch
#define SMEM_BYTES (SCR_OFF + NWAVES * 2048)   // 140800 B

__device__ __forceinline__ unsigned short f2bf(float x) {
    unsigned u = __builtin_bit_cast(unsigned, x);
    return (unsigned short)((u + 0x7FFFu + ((u >> 16) & 1u)) >> 16);
}

__global__ __launch_bounds__(THREADS, 4) void leg_mfma(
    const float* __restrict__ z, const float* __restrict__ T,
    const float* __restrict__ Cm, const float* __restrict__ beta,
    float* __restrict__ out)
{
    extern __shared__ char smem[];
    float* scale_s = (float*)(smem + SCALE_OFF);
    const int tid  = (int)threadIdx.x;
    const int lane = tid & 63;
    const int wv   = tid >> 6;
    const int lrow = lane & 15;          // row (A-op) / col (C/D) index
    const int lhi  = lane >> 4;          // 0..3

    // ---------- phase A: per-row scales: j==0 -> 1, else coef_j / rowsum ----
    if (tid < 384) {
        const int mat = tid >> 6, kc = tid & 63;
        const float4* tr = (const float4*)(T + (size_t)((mat << 6) + kc) * 64);
        float s = 0.f;
        #pragma unroll
        for (int q = 0; q < 16; ++q) { float4 v = tr[q]; s += v.x + v.y + v.z + v.w; }
        float sc;
        if (mat == 0) sc = 1.f;
        else { const float fi = (float)(mat + 1); sc = (2.f * fi - 1.f) / fi / s; }
        scale_s[tid] = sc;
    }
    __syncthreads();

    // ---------- phase B: build B-operand frags of A (f16 hi/lo) -------------
    // frag(mat,s,f): lane l supplies B[k=(l>>4)*8+j][col=(l&15)+16f] of the
    // d-range 32s..32s+31, i.e. A[col][32s+(l>>4)*8+j] * scale.
    for (int g = tid; g < 3072; g += THREADS) {
        const int mat = g >> 9;
        const int s   = (g >> 8) & 1;
        const int f   = (g >> 6) & 3;
        const int l   = g & 63;
        const int kc  = (l & 15) + (f << 4);
        const int d0  = ((l >> 4) << 3) + (s << 5);
        const float sc = scale_s[(mat << 6) + kc];
        const float* src = T + (size_t)((mat << 6) + kc) * 64 + d0;
        const float4 v0 = *(const float4*)(src);
        const float4 v1 = *(const float4*)(src + 4);
        const float vv[8] = {v0.x, v0.y, v0.z, v0.w, v1.x, v1.y, v1.z, v1.w};
        f16x8 hi, lo;
        #pragma unroll
        for (int j = 0; j < 8; ++j) {
            const float x = vv[j] * sc;
            const _Float16 h = (_Float16)x;
            hi[j] = h;
            lo[j] = (_Float16)(x - (float)h);
        }
        const int fr = (((mat << 1) + s) << 2) + f;
        *(f16x8*)(smem + BH_OFF + fr * 1024 + l * 16) = hi;
        *(f16x8*)(smem + BL_OFF + fr * 1024 + l * 16) = lo;
    }
    // C-operand frags (bf16 hi/lo): frag(hl,s,fo): lane l supplies
    // C2[k=32s+(l>>4)*8+j][o=(l&15)+16fo] = C[o][k].
    if (tid < 512) {
        const int hl = (tid >> 8) & 1;
        const int s  = (tid >> 7) & 1;
        const int fo = (tid >> 6) & 1;
        const int l  = tid & 63;
        const int o  = (l & 15) + (fo << 4);
        const int k0 = ((l >> 4) << 3) + (s << 5);
        const float* src = Cm + (size_t)o * 64 + k0;
        const float4 v0 = *(const float4*)src;
        const float4 v1 = *(const float4*)(src + 4);
        const float vv[8] = {v0.x, v0.y, v0.z, v0.w, v1.x, v1.y, v1.z, v1.w};
        s16x8 fr;
        #pragma unroll
        for (int j = 0; j < 8; ++j) {
            const float x = vv[j];
            const unsigned short h = f2bf(x);
            if (hl) {
                const float hf = __builtin_bit_cast(float, (unsigned)h << 16);
                fr[j] = (short)f2bf(x - hf);
            } else {
                fr[j] = (short)h;
            }
        }
        *(s16x8*)(smem + CF_OFF + ((((hl << 1) + s) << 1) + fo) * 1024 + l * 16) = fr;
    }
    __syncthreads();

    // ---------- main: each wave owns 128 rows, 4 iters of 32 rows -----------
    const int    gw      = blockIdx.x * NWAVES + wv;
    const size_t rowbase = (size_t)gw * ROWS_PER_WAVE;
    float* scr = (float*)(smem + SCR_OFF) + wv * 512;   // 16 rows x 32 f32

    const float beta0 = beta[lrow];
    const float beta1 = beta[16 + lrow];

    f16x8 zh[2][2], zl[2][2];

    // one Legendre level: PT := W_mat * PC - b * PT, W folded per-fragment
    auto leg_step = [&](int mat, float b, f32x4 (&PC)[2][4], f32x4 (&PT)[2][4]) {
        #pragma unroll
        for (int f = 0; f < 4; ++f) {
            const int fr0 = mat * 8 + f;       // s=0
            const int fr1 = mat * 8 + 4 + f;   // s=1
            const f16x8 bh0 = *(const f16x8*)(smem + BH_OFF + fr0 * 1024 + lane * 16);
            const f16x8 bl0 = *(const f16x8*)(smem + BL_OFF + fr0 * 1024 + lane * 16);
            const f16x8 bh1 = *(const f16x8*)(smem + BH_OFF + fr1 * 1024 + lane * 16);
            const f16x8 bl1 = *(const f16x8*)(smem + BL_OFF + fr1 * 1024 + lane * 16);
            #pragma unroll
            for (int t = 0; t < 2; ++t) {
                f32x4 a = {0.f, 0.f, 0.f, 0.f};
                a = __builtin_amdgcn_mfma_f32_16x16x32_f16(zh[t][0], bh0, a, 0, 0, 0);
                a = __builtin_amdgcn_mfma_f32_16x16x32_f16(zl[t][0], bh0, a, 0, 0, 0);
                a = __builtin_amdgcn_mfma_f32_16x16x32_f16(zh[t][0], bl0, a, 0, 0, 0);
                a = __builtin_amdgcn_mfma_f32_16x16x32_f16(zh[t][1], bh1, a, 0, 0, 0);
                a = __builtin_amdgcn_mfma_f32_16x16x32_f16(zl[t][1], bh1, a, 0, 0, 0);
                a = __builtin_amdgcn_mfma_f32_16x16x32_f16(zh[t][1], bl1, a, 0, 0, 0);
                #pragma unroll
                for (int r = 0; r < 4; ++r)
                    PT[t][f][r] = a[r] * PC[t][f][r] - b * PT[t][f][r];
            }
        }
    };

    // prologue: load z for iter 0
    float4 zraw[2][4];
    #pragma unroll
    for (int t = 0; t < 2; ++t)
        #pragma unroll
        for (int s = 0; s < 2; ++s) {
            const float* p = z + (rowbase + t * 16 + lrow) * 64 + (s << 5) + (lhi << 3);
            zraw[t][2 * s]     = *(const float4*)(p);
            zraw[t][2 * s + 1] = *(const float4*)(p + 4);
        }

    for (int it = 0; it < NITER; ++it) {
        // convert staged z to f16 hi/lo fragments
        #pragma unroll
        for (int t = 0; t < 2; ++t)
            #pragma unroll
            for (int s = 0; s < 2; ++s) {
                const float4 q0 = zraw[t][2 * s], q1 = zraw[t][2 * s + 1];
                const float vv[8] = {q0.x, q0.y, q0.z, q0.w, q1.x, q1.y, q1.z, q1.w};
                #pragma unroll
                for (int j = 0; j < 8; ++j) {
                    const _Float16 h = (_Float16)vv[j];
                    zh[t][s][j] = h;
                    zl[t][s][j] = (_Float16)(vv[j] - (float)h);
                }
            }
        // prefetch next iter's z (in flight across the mat loop)
        if (it < NITER - 1) {
            #pragma unroll
            for (int t = 0; t < 2; ++t)
                #pragma unroll
                for (int s = 0; s < 2; ++s) {
                    const float* p = z + (rowbase + (it + 1) * 32 + t * 16 + lrow) * 64
                                       + (s << 5) + (lhi << 3);
                    zraw[t][2 * s]     = *(const float4*)(p);
                    zraw[t][2 * s + 1] = *(const float4*)(p + 4);
                }
        }

        // Legendre chain: pA = P1, pB = P2, then ping-pong; P6 ends in pB
        f32x4 pA[2][4], pB[2][4];
        // mat 0 -> pA  (P1)
        #pragma unroll
        for (int f = 0; f < 4; ++f) {
            const int fr0 = f, fr1 = 4 + f;
            const f16x8 bh0 = *(const f16x8*)(smem + BH_OFF + fr0 * 1024 + lane * 16);
            const f16x8 bl0 = *(const f16x8*)(smem + BL_OFF + fr0 * 1024 + lane * 16);
            const f16x8 bh1 = *(const f16x8*)(smem + BH_OFF + fr1 * 1024 + lane * 16);
            const f16x8 bl1 = *(const f16x8*)(smem + BL_OFF + fr1 * 1024 + lane * 16);
            #pragma unroll
            for (int t = 0; t < 2; ++t) {
                f32x4 a = {0.f, 0.f, 0.f, 0.f};
                a = __builtin_amdgcn_mfma_f32_16x16x32_f16(zh[t][0], bh0, a, 0, 0, 0);
                a = __builtin_amdgcn_mfma_f32_16x16x32_f16(zl[t][0], bh0, a, 0, 0, 0);
                a = __builtin_amdgcn_mfma_f32_16x16x32_f16(zh[t][0], bl0, a, 0, 0, 0);
                a = __builtin_amdgcn_mfma_f32_16x16x32_f16(zh[t][1], bh1, a, 0, 0, 0);
                a = __builtin_amdgcn_mfma_f32_16x16x32_f16(zl[t][1], bh1, a, 0, 0, 0);
                a = __builtin_amdgcn_mfma_f32_16x16x32_f16(zh[t][1], bl1, a, 0, 0, 0);
                pA[t][f] = a;
            }
        }
        // mat 1 -> pB = W2*pA - 0.5  (P2; P0 = ones)
        #pragma unroll
        for (int f = 0; f < 4; ++f) {
            const int fr0 = 8 + f, fr1 = 12 + f;
            const f16x8 bh0 = *(const f16x8*)(smem + BH_OFF + fr0 * 1024 + lane * 16);
            const f16x8 bl0 = *(const f16x8*)(smem + BL_OFF + fr0 * 1024 + lane * 16);
            const f16x8 bh1 = *(const f16x8*)(smem + BH_OFF + fr1 * 1024 + lane * 16);
            const f16x8 bl1 = *(const f16x8*)(smem + BL_OFF + fr1 * 1024 + lane * 16);
            #pragma unroll
            for (int t = 0; t < 2; ++t) {
                f32x4 a = {0.f, 0.f, 0.f, 0.f};
                a = __builtin_amdgcn_mfma_f32_16x16x32_f16(zh[t][0], bh0, a, 0, 0, 0);
                a = __builtin_amdgcn_mfma_f32_16x16x32_f16(zl[t][0], bh0, a, 0, 0, 0);
                a = __builtin_amdgcn_mfma_f32_16x16x32_f16(zh[t][0], bl0, a, 0, 0, 0);
                a = __builtin_amdgcn_mfma_f32_16x16x32_f16(zh[t][1], bh1, a, 0, 0, 0);
                a = __builtin_amdgcn_mfma_f32_16x16x32_f16(zl[t][1], bh1, a, 0, 0, 0);
                a = __builtin_amdgcn_mfma_f32_16x16x32_f16(zh[t][1], bl1, a, 0, 0, 0);
                #pragma unroll
                for (int r = 0; r < 4; ++r)
                    pB[t][f][r] = a[r] * pA[t][f][r] - 0.5f;
            }
        }
        leg_step(2, 2.f / 3.f, pB, pA);   // P3
        leg_step(3, 3.f / 4.f, pA, pB);   // P4
        leg_step(4, 4.f / 5.f, pB, pA);   // P5
        leg_step(5, 5.f / 6.f, pA, pB);   // P6 = pB

        // ---------------- epilogue: out = P6 @ C^T + beta -------------------
        s16x8 ch[2][2], cl[2][2];   // [s][fo]
        #pragma unroll
        for (int s = 0; s < 2; ++s)
            #pragma unroll
            for (int fo = 0; fo < 2; ++fo) {
                ch[s][fo] = *(const s16x8*)(smem + CF_OFF + ((s << 1) + fo) * 1024 + lane * 16);
                cl[s][fo] = *(const s16x8*)(smem + CF_OFF + (((2 + s) << 1) + fo) * 1024 + lane * 16);
            }
        #pragma unroll
        for (int t = 0; t < 2; ++t) {
            // transpose P6 (C/D layout) -> A-op layout, two k-32 phases through
            // a 16x32 XOR-swizzled scratch (2 KB/wave)
            s16x8 p6h[2], p6l[2];
            #pragma unroll
            for (int s = 0; s < 2; ++s) {
                #pragma unroll
                for (int f_ = 0; f_ < 2; ++f_) {
                    const int f    = 2 * s + f_;
                    const int colp = (f_ << 4) + lrow;
                    #pragma unroll
                    for (int r = 0; r < 4; ++r) {
                        const int row = lhi * 4 + r;
                        const int g4  = ((colp >> 2) ^ row) & 7;
                        scr[row * 32 + g4 * 4 + (colp & 3)] = pB[t][f][r];
                    }
                }
                // wave-synchronous read-back (compiler inserts lgkmcnt wait)
                float vv[8];
                #pragma unroll
                for (int jg = 0; jg < 2; ++jg) {
                    const int g4r = (((lhi << 1) + jg) ^ lrow) & 7;
                    const float4 q = *(const float4*)(scr + lrow * 32 + g4r * 4);
                    vv[jg * 4 + 0] = q.x; vv[jg * 4 + 1] = q.y;
                    vv[jg * 4 + 2] = q.z; vv[jg * 4 + 3] = q.w;
                }
                #pragma unroll
                for (int j = 0; j < 8; ++j) {
                    const unsigned short h = f2bf(vv[j]);
                    const float hf = __builtin_bit_cast(float, (unsigned)h << 16);
                    p6h[s][j] = (short)h;
                    p6l[s][j] = (short)f2bf(vv[j] - hf);
                }
            }
            #pragma unroll
            for (int fo = 0; fo < 2; ++fo) {
                f32x4 o = {0.f, 0.f, 0.f, 0.f};
                o = __builtin_amdgcn_mfma_f32_16x16x32_bf16(p6h[0], ch[0][fo], o, 0, 0, 0);
                o = __builtin_amdgcn_mfma_f32_16x16x32_bf16(p6l[0], ch[0][fo], o, 0, 0, 0);
                o = __builtin_amdgcn_mfma_f32_16x16x32_bf16(p6h[0], cl[0][fo], o, 0, 0, 0);
                o = __builtin_amdgcn_mfma_f32_16x16x32_bf16(p6h[1], ch[1][fo], o, 0, 0, 0);
                o = __builtin_amdgcn_mfma_f32_16x16x32_bf16(p6l[1], ch[1][fo], o, 0, 0, 0);
                o = __builtin_amdgcn_mfma_f32_16x16x32_bf16(p6h[1], cl[1][fo], o, 0, 0, 0);
                const float bb = fo ? beta1 : beta0;
                const size_t r0 = rowbase + (size_t)it * 32 + t * 16 + lhi * 4;
                #pragma unroll
                for (int r = 0; r < 4; ++r)
                    out[(r0 + r) * 32 + (fo << 4) + lrow] = o[r] + bb;
            }
        }
    }
}

extern "C" void kernel_launch(void* const* d_in, const int* in_sizes, int n_in,
                              void* d_out, int out_size, void* d_ws, size_t ws_size,
                              hipStream_t stream) {
    const float* z    = (const float*)d_in[0];
    const float* T    = (const float*)d_in[1];
    const float* C    = (const float*)d_in[2];
    const float* beta = (const float*)d_in[3];
    float* out = (float*)d_out;
    (void)in_sizes; (void)n_in; (void)out_size; (void)d_ws; (void)ws_size;

    hipFuncSetAttribute((const void*)leg_mfma,
                        hipFuncAttributeMaxDynamicSharedMemorySize, SMEM_BYTES);
    leg_mfma<<<BLOCKS, THREADS, SMEM_BYTES, stream>>>(z, T, C, beta, out);
}

// Round 4
// 90.982 us; speedup vs baseline: 1.3051x; 1.3051x over previous
//
#include <hip/hip_runtime.h>

// Legendre2 via split-precision MFMA, v4: 16-wave blocks, no launch-bounds
// min-waves arg (v3's ",4" forced a 64-VGPR budget -> massive scratch spills).
// W_i = Z @ (coef_i * Tnorm_i)^T  as f16 hi/lo 3-term MFMA (f32 accum),
// elementwise Legendre fold in f32 regs, epilogue P6 @ C^T + beta as
// bf16 hi/lo 3-term MFMA. N=524288, D=64, K=64, O=32, DEGREE=6.

typedef _Float16 f16x8 __attribute__((ext_vector_type(8)));
typedef short    s16x8 __attribute__((ext_vector_type(8)));
typedef float    f32x4 __attribute__((ext_vector_type(4)));

#define NN      524288
#define BLOCKS  256
#define THREADS 1024
#define NWAVES  16
#define ROWS_PER_WAVE 128
#define NITER   4                        // 4 x 32 rows per wave

// LDS byte offsets
#define BH_OFF    0                      // 48 frags * 1 KB (f16 hi of A)
#define BL_OFF    49152                  // 48 frags * 1 KB (f16 lo of A)
#define CF_OFF    98304                  // 8 frags * 1 KB (bf16 h/l of C)
#define SCALE_OFF 106496                 // 384 f32 scales
#define SCR_OFF   108032                 // 16 waves * 2 KB transpose scratch
#define SMEM_BYTES (SCR_OFF + NWAVES * 2048)   // 140800 B

__device__ __forceinline__ unsigned short f2bf(float x) {
    unsigned u = __builtin_bit_cast(unsigned, x);
    return (unsigned short)((u + 0x7FFFu + ((u >> 16) & 1u)) >> 16);
}

__global__ __launch_bounds__(THREADS) void leg_mfma(
    const float* __restrict__ z, const float* __restrict__ T,
    const float* __restrict__ Cm, const float* __restrict__ beta,
    float* __restrict__ out)
{
    extern __shared__ char smem[];
    float* scale_s = (float*)(smem + SCALE_OFF);
    const int tid  = (int)threadIdx.x;
    const int lane = tid & 63;
    const int wv   = tid >> 6;
    const int lrow = lane & 15;          // row (A-op) / col (C/D) index
    const int lhi  = lane >> 4;          // 0..3

    // ---------- phase A: per-row scales: j==0 -> 1, else coef_j / rowsum ----
    if (tid < 384) {
        const int mat = tid >> 6, kc = tid & 63;
        const float4* tr = (const float4*)(T + (size_t)((mat << 6) + kc) * 64);
        float s = 0.f;
        #pragma unroll
        for (int q = 0; q < 16; ++q) { float4 v = tr[q]; s += v.x + v.y + v.z + v.w; }
        float sc;
        if (mat == 0) sc = 1.f;
        else { const float fi = (float)(mat + 1); sc = (2.f * fi - 1.f) / fi / s; }
        scale_s[tid] = sc;
    }
    __syncthreads();

    // ---------- phase B: build B-operand frags of A (f16 hi/lo) -------------
    // frag(mat,s,f): lane l supplies B[k=(l>>4)*8+j][col=(l&15)+16f] of the
    // d-range 32s..32s+31, i.e. A[col][32s+(l>>4)*8+j] * scale.
    for (int g = tid; g < 3072; g += THREADS) {
        const int mat = g >> 9;
        const int s   = (g >> 8) & 1;
        const int f   = (g >> 6) & 3;
        const int l   = g & 63;
        const int kc  = (l & 15) + (f << 4);
        const int d0  = ((l >> 4) << 3) + (s << 5);
        const float sc = scale_s[(mat << 6) + kc];
        const float* src = T + (size_t)((mat << 6) + kc) * 64 + d0;
        const float4 v0 = *(const float4*)(src);
        const float4 v1 = *(const float4*)(src + 4);
        const float vv[8] = {v0.x, v0.y, v0.z, v0.w, v1.x, v1.y, v1.z, v1.w};
        f16x8 hi, lo;
        #pragma unroll
        for (int j = 0; j < 8; ++j) {
            const float x = vv[j] * sc;
            const _Float16 h = (_Float16)x;
            hi[j] = h;
            lo[j] = (_Float16)(x - (float)h);
        }
        const int fr = (((mat << 1) + s) << 2) + f;
        *(f16x8*)(smem + BH_OFF + fr * 1024 + l * 16) = hi;
        *(f16x8*)(smem + BL_OFF + fr * 1024 + l * 16) = lo;
    }
    // C-operand frags (bf16 hi/lo): frag(hl,s,fo): lane l supplies
    // C2[k=32s+(l>>4)*8+j][o=(l&15)+16fo] = C[o][k].
    if (tid < 512) {
        const int hl = (tid >> 8) & 1;
        const int s  = (tid >> 7) & 1;
        const int fo = (tid >> 6) & 1;
        const int l  = tid & 63;
        const int o  = (l & 15) + (fo << 4);
        const int k0 = ((l >> 4) << 3) + (s << 5);
        const float* src = Cm + (size_t)o * 64 + k0;
        const float4 v0 = *(const float4*)src;
        const float4 v1 = *(const float4*)(src + 4);
        const float vv[8] = {v0.x, v0.y, v0.z, v0.w, v1.x, v1.y, v1.z, v1.w};
        s16x8 fr;
        #pragma unroll
        for (int j = 0; j < 8; ++j) {
            const float x = vv[j];
            const unsigned short h = f2bf(x);
            if (hl) {
                const float hf = __builtin_bit_cast(float, (unsigned)h << 16);
                fr[j] = (short)f2bf(x - hf);
            } else {
                fr[j] = (short)h;
            }
        }
        *(s16x8*)(smem + CF_OFF + ((((hl << 1) + s) << 1) + fo) * 1024 + l * 16) = fr;
    }
    __syncthreads();

    // ---------- main: each wave owns 128 rows, 4 iters of 32 rows -----------
    const int    gw      = blockIdx.x * NWAVES + wv;
    const size_t rowbase = (size_t)gw * ROWS_PER_WAVE;
    float* scr = (float*)(smem + SCR_OFF) + wv * 512;   // 16 rows x 32 f32

    const float beta0 = beta[lrow];
    const float beta1 = beta[16 + lrow];

    f16x8 zh[2][2], zl[2][2];

    // one Legendre level: PT := W_mat * PC - b * PT, W folded per-fragment
    auto leg_step = [&](int mat, float b, f32x4 (&PC)[2][4], f32x4 (&PT)[2][4]) {
        #pragma unroll
        for (int f = 0; f < 4; ++f) {
            const int fr0 = mat * 8 + f;       // s=0
            const int fr1 = mat * 8 + 4 + f;   // s=1
            const f16x8 bh0 = *(const f16x8*)(smem + BH_OFF + fr0 * 1024 + lane * 16);
            const f16x8 bl0 = *(const f16x8*)(smem + BL_OFF + fr0 * 1024 + lane * 16);
            const f16x8 bh1 = *(const f16x8*)(smem + BH_OFF + fr1 * 1024 + lane * 16);
            const f16x8 bl1 = *(const f16x8*)(smem + BL_OFF + fr1 * 1024 + lane * 16);
            #pragma unroll
            for (int t = 0; t < 2; ++t) {
                f32x4 a = {0.f, 0.f, 0.f, 0.f};
                a = __builtin_amdgcn_mfma_f32_16x16x32_f16(zh[t][0], bh0, a, 0, 0, 0);
                a = __builtin_amdgcn_mfma_f32_16x16x32_f16(zl[t][0], bh0, a, 0, 0, 0);
                a = __builtin_amdgcn_mfma_f32_16x16x32_f16(zh[t][0], bl0, a, 0, 0, 0);
                a = __builtin_amdgcn_mfma_f32_16x16x32_f16(zh[t][1], bh1, a, 0, 0, 0);
                a = __builtin_amdgcn_mfma_f32_16x16x32_f16(zl[t][1], bh1, a, 0, 0, 0);
                a = __builtin_amdgcn_mfma_f32_16x16x32_f16(zh[t][1], bl1, a, 0, 0, 0);
                #pragma unroll
                for (int r = 0; r < 4; ++r)
                    PT[t][f][r] = a[r] * PC[t][f][r] - b * PT[t][f][r];
            }
        }
    };

    for (int it = 0; it < NITER; ++it) {
        // load + convert z for this iter (no software prefetch: 4 waves/EU of
        // TLP hides the latency; freeing zraw across the mat-chain keeps the
        // kernel spill-free at the 128-VGPR tier)
        #pragma unroll
        for (int t = 0; t < 2; ++t)
            #pragma unroll
            for (int s = 0; s < 2; ++s) {
                const float* p = z + (rowbase + (size_t)it * 32 + t * 16 + lrow) * 64
                                   + (s << 5) + (lhi << 3);
                const float4 q0 = *(const float4*)(p);
                const float4 q1 = *(const float4*)(p + 4);
                const float vv[8] = {q0.x, q0.y, q0.z, q0.w, q1.x, q1.y, q1.z, q1.w};
                #pragma unroll
                for (int j = 0; j < 8; ++j) {
                    const _Float16 h = (_Float16)vv[j];
                    zh[t][s][j] = h;
                    zl[t][s][j] = (_Float16)(vv[j] - (float)h);
                }
            }

        // Legendre chain: pA = P1, pB = P2, then ping-pong; P6 ends in pB
        f32x4 pA[2][4], pB[2][4];
        // mat 0 -> pA  (P1)
        #pragma unroll
        for (int f = 0; f < 4; ++f) {
            const int fr0 = f, fr1 = 4 + f;
            const f16x8 bh0 = *(const f16x8*)(smem + BH_OFF + fr0 * 1024 + lane * 16);
            const f16x8 bl0 = *(const f16x8*)(smem + BL_OFF + fr0 * 1024 + lane * 16);
            const f16x8 bh1 = *(const f16x8*)(smem + BH_OFF + fr1 * 1024 + lane * 16);
            const f16x8 bl1 = *(const f16x8*)(smem + BL_OFF + fr1 * 1024 + lane * 16);
            #pragma unroll
            for (int t = 0; t < 2; ++t) {
                f32x4 a = {0.f, 0.f, 0.f, 0.f};
                a = __builtin_amdgcn_mfma_f32_16x16x32_f16(zh[t][0], bh0, a, 0, 0, 0);
                a = __builtin_amdgcn_mfma_f32_16x16x32_f16(zl[t][0], bh0, a, 0, 0, 0);
                a = __builtin_amdgcn_mfma_f32_16x16x32_f16(zh[t][0], bl0, a, 0, 0, 0);
                a = __builtin_amdgcn_mfma_f32_16x16x32_f16(zh[t][1], bh1, a, 0, 0, 0);
                a = __builtin_amdgcn_mfma_f32_16x16x32_f16(zl[t][1], bh1, a, 0, 0, 0);
                a = __builtin_amdgcn_mfma_f32_16x16x32_f16(zh[t][1], bl1, a, 0, 0, 0);
                pA[t][f] = a;
            }
        }
        // mat 1 -> pB = W2*pA - 0.5  (P2; P0 = ones)
        #pragma unroll
        for (int f = 0; f < 4; ++f) {
            const int fr0 = 8 + f, fr1 = 12 + f;
            const f16x8 bh0 = *(const f16x8*)(smem + BH_OFF + fr0 * 1024 + lane * 16);
            const f16x8 bl0 = *(const f16x8*)(smem + BL_OFF + fr0 * 1024 + lane * 16);
            const f16x8 bh1 = *(const f16x8*)(smem + BH_OFF + fr1 * 1024 + lane * 16);
            const f16x8 bl1 = *(const f16x8*)(smem + BL_OFF + fr1 * 1024 + lane * 16);
            #pragma unroll
            for (int t = 0; t < 2; ++t) {
                f32x4 a = {0.f, 0.f, 0.f, 0.f};
                a = __builtin_amdgcn_mfma_f32_16x16x32_f16(zh[t][0], bh0, a, 0, 0, 0);
                a = __builtin_amdgcn_mfma_f32_16x16x32_f16(zl[t][0], bh0, a, 0, 0, 0);
                a = __builtin_amdgcn_mfma_f32_16x16x32_f16(zh[t][0], bl0, a, 0, 0, 0);
                a = __builtin_amdgcn_mfma_f32_16x16x32_f16(zh[t][1], bh1, a, 0, 0, 0);
                a = __builtin_amdgcn_mfma_f32_16x16x32_f16(zl[t][1], bh1, a, 0, 0, 0);
                a = __builtin_amdgcn_mfma_f32_16x16x32_f16(zh[t][1], bl1, a, 0, 0, 0);
                #pragma unroll
                for (int r = 0; r < 4; ++r)
                    pB[t][f][r] = a[r] * pA[t][f][r] - 0.5f;
            }
        }
        leg_step(2, 2.f / 3.f, pB, pA);   // P3
        leg_step(3, 3.f / 4.f, pA, pB);   // P4
        leg_step(4, 4.f / 5.f, pB, pA);   // P5
        leg_step(5, 5.f / 6.f, pA, pB);   // P6 = pB

        // ---------------- epilogue: out = P6 @ C^T + beta -------------------
        s16x8 ch[2][2], cl[2][2];   // [s][fo]
        #pragma unroll
        for (int s = 0; s < 2; ++s)
            #pragma unroll
            for (int fo = 0; fo < 2; ++fo) {
                ch[s][fo] = *(const s16x8*)(smem + CF_OFF + ((s << 1) + fo) * 1024 + lane * 16);
                cl[s][fo] = *(const s16x8*)(smem + CF_OFF + (((2 + s) << 1) + fo) * 1024 + lane * 16);
            }
        #pragma unroll
        for (int t = 0; t < 2; ++t) {
            // transpose P6 (C/D layout) -> A-op layout, two k-32 phases through
            // a 16x32 XOR-swizzled scratch (2 KB/wave)
            s16x8 p6h[2], p6l[2];
            #pragma unroll
            for (int s = 0; s < 2; ++s) {
                #pragma unroll
                for (int f_ = 0; f_ < 2; ++f_) {
                    const int f    = 2 * s + f_;
                    const int colp = (f_ << 4) + lrow;
                    #pragma unroll
                    for (int r = 0; r < 4; ++r) {
                        const int row = lhi * 4 + r;
                        const int g4  = ((colp >> 2) ^ row) & 7;
                        scr[row * 32 + g4 * 4 + (colp & 3)] = pB[t][f][r];
                    }
                }
                // wave-synchronous read-back (compiler inserts lgkmcnt wait)
                float vv[8];
                #pragma unroll
                for (int jg = 0; jg < 2; ++jg) {
                    const int g4r = (((lhi << 1) + jg) ^ lrow) & 7;
                    const float4 q = *(const float4*)(scr + lrow * 32 + g4r * 4);
                    vv[jg * 4 + 0] = q.x; vv[jg * 4 + 1] = q.y;
                    vv[jg * 4 + 2] = q.z; vv[jg * 4 + 3] = q.w;
                }
                #pragma unroll
                for (int j = 0; j < 8; ++j) {
                    const unsigned short h = f2bf(vv[j]);
                    const float hf = __builtin_bit_cast(float, (unsigned)h << 16);
                    p6h[s][j] = (short)h;
                    p6l[s][j] = (short)f2bf(vv[j] - hf);
                }
            }
            #pragma unroll
            for (int fo = 0; fo < 2; ++fo) {
                f32x4 o = {0.f, 0.f, 0.f, 0.f};
                o = __builtin_amdgcn_mfma_f32_16x16x32_bf16(p6h[0], ch[0][fo], o, 0, 0, 0);
                o = __builtin_amdgcn_mfma_f32_16x16x32_bf16(p6l[0], ch[0][fo], o, 0, 0, 0);
                o = __builtin_amdgcn_mfma_f32_16x16x32_bf16(p6h[0], cl[0][fo], o, 0, 0, 0);
                o = __builtin_amdgcn_mfma_f32_16x16x32_bf16(p6h[1], ch[1][fo], o, 0, 0, 0);
                o = __builtin_amdgcn_mfma_f32_16x16x32_bf16(p6l[1], ch[1][fo], o, 0, 0, 0);
                o = __builtin_amdgcn_mfma_f32_16x16x32_bf16(p6h[1], cl[1][fo], o, 0, 0, 0);
                const float bb = fo ? beta1 : beta0;
                const size_t r0 = rowbase + (size_t)it * 32 + t * 16 + lhi * 4;
                #pragma unroll
                for (int r = 0; r < 4; ++r)
                    out[(r0 + r) * 32 + (fo << 4) + lrow] = o[r] + bb;
            }
        }
    }
}

extern "C" void kernel_launch(void* const* d_in, const int* in_sizes, int n_in,
                              void* d_out, int out_size, void* d_ws, size_t ws_size,
                              hipStream_t stream) {
    const float* z    = (const float*)d_in[0];
    const float* T    = (const float*)d_in[1];
    const float* C    = (const float*)d_in[2];
    const float* beta = (const float*)d_in[3];
    float* out = (float*)d_out;
    (void)in_sizes; (void)n_in; (void)out_size; (void)d_ws; (void)ws_size;

    hipFuncSetAttribute((const void*)leg_mfma,
                        hipFuncAttributeMaxDynamicSharedMemorySize, SMEM_BYTES);
    leg_mfma<<<BLOCKS, THREADS, SMEM_BYTES, stream>>>(z, T, C, beta, out);
}